// Round 4
// baseline (4098.073 us; speedup 1.0000x reference)
//
#include <hip/hip_runtime.h>

#define FDIM 256
#define GRAM_KS 128

// ---------------- CSR build ----------------
__global__ void k_hist(const int* __restrict__ dst, int* __restrict__ deg, int E) {
  int e = blockIdx.x * 256 + threadIdx.x;
  if (e < E) atomicAdd(&deg[dst[e]], 1);
}

__global__ __launch_bounds__(256) void k_blksum(const int* __restrict__ deg,
    int* __restrict__ blksum, int n) {
  int b = blockIdx.x, tid = threadIdx.x;
  int base = b * 1024 + tid * 4;
  int s = 0;
#pragma unroll
  for (int k = 0; k < 4; ++k) if (base + k < n) s += deg[base + k];
  for (int off = 32; off; off >>= 1) s += __shfl_down(s, off);
  __shared__ int ws4[4];
  if ((tid & 63) == 0) ws4[tid >> 6] = s;
  __syncthreads();
  if (tid == 0) blksum[b] = ws4[0] + ws4[1] + ws4[2] + ws4[3];
}

__global__ void k_blkscan(const int* __restrict__ blksum, int* __restrict__ blkoff, int nblk) {
  int lane = threadIdx.x;
  int carry = 0;
  for (int base = 0; base < nblk; base += 64) {
    int v = (base + lane < nblk) ? blksum[base + lane] : 0;
    int x = v;
    for (int off = 1; off < 64; off <<= 1) { int y = __shfl_up(x, off); if (lane >= off) x += y; }
    if (base + lane < nblk) blkoff[base + lane] = carry + x - v;
    carry += __shfl(x, 63);
  }
}

__global__ __launch_bounds__(256) void k_scan_blk(const int* __restrict__ deg,
    const int* __restrict__ blkoff, int* __restrict__ rowptr, int* __restrict__ cursor, int n) {
  int b = blockIdx.x, tid = threadIdx.x;
  int base = b * 1024 + tid * 4;
  int v[4];
#pragma unroll
  for (int k = 0; k < 4; ++k) v[k] = (base + k < n) ? deg[base + k] : 0;
  int s = v[0] + v[1] + v[2] + v[3];
  int lane = tid & 63, w = tid >> 6;
  int x = s;
  for (int off = 1; off < 64; off <<= 1) { int y = __shfl_up(x, off); if (lane >= off) x += y; }
  __shared__ int wsum[4];
  if (lane == 63) wsum[w] = x;
  __syncthreads();
  int wadd = 0;
  for (int i = 0; i < w; ++i) wadd += wsum[i];
  int run = blkoff[b] + wadd + x - s;
#pragma unroll
  for (int k = 0; k < 4; ++k) {
    if (base + k < n) { rowptr[base + k] = run; cursor[base + k] = run; }
    run += v[k];
  }
  if (n >= base && n <= base + 4) rowptr[n] = run;
}

__global__ void k_scatter(const int* __restrict__ src, const int* __restrict__ dst,
    int* __restrict__ cursor, int* __restrict__ esrc, int E) {
  int e = blockIdx.x * 256 + threadIdx.x;
  if (e < E) {
    int p = atomicAdd(&cursor[dst[e]], 1);
    esrc[p] = src[e];
  }
}

// ---------------- layout transform: row-major F -> planar FP ----------------
// planar: FP[((plane*N + node)*16 + c] ; plane=col>>4, c=col&15
__global__ __launch_bounds__(256) void k_to_planar(const float* __restrict__ F,
    float* __restrict__ FP, int N) {
  int n = blockIdx.x * 4 + (threadIdx.x >> 6);
  int ic = threadIdx.x & 63;
#pragma unroll
  for (int q = 0; q < 4; ++q) {
    int col = q * 64 + ic;
    FP[((size_t)(col >> 4) * N + n) * 16 + (col & 15)] = F[(size_t)n * 256 + col];
  }
}

// ---------------- planar aggregation, XCD-pinned column planes ----------------
// chunk c7 = blockIdx.x & 7 -> XCD c7 (round-robin heuristic); block does planes c7, c7+8.
// One wave per node: 4 edge-slots x 16 cols.
__global__ __launch_bounds__(256) void k_aggp(const float* __restrict__ src,
    const int* __restrict__ rowptr, const int* __restrict__ esrc,
    float* __restrict__ out, int N, int rowmajor) {
  int c7 = blockIdx.x & 7;
  int n = (blockIdx.x >> 3) * 4 + (threadIdx.x >> 6);
  int lane = threadIdx.x & 63;
  int cl = lane & 15, es = lane >> 4;
  int beg = rowptr[n], end = rowptr[n + 1];
  size_t stride = rowmajor ? 256 : 16;
#pragma unroll
  for (int sub = 0; sub < 2; ++sub) {
    int plane = c7 + 8 * sub;
    const float* base = rowmajor ? (src + plane * 16 + cl)
                                 : (src + ((size_t)plane * N) * 16 + cl);
    float acc = 0.f, acc2 = 0.f;
    int e = beg + es;
    for (; e + 4 < end; e += 8) {
      int s0 = esrc[e], s1 = esrc[e + 4];
      acc  += base[(size_t)s0 * stride];
      acc2 += base[(size_t)s1 * stride];
    }
    if (e < end) acc += base[(size_t)esrc[e] * stride];
    acc += acc2;
    acc += __shfl_down(acc, 32);
    acc += __shfl_down(acc, 16);
    if (lane < 16)
      __builtin_nontemporal_store(acc, &out[((size_t)plane * N + n) * 16 + lane]);
  }
}

// ---------------- scalar aggregation ----------------
__global__ void k_deg(const int* __restrict__ rowptr, float* __restrict__ out, int n) {
  int v = blockIdx.x * 256 + threadIdx.x;
  if (v < n) out[v] = (float)(rowptr[v + 1] - rowptr[v]);
}

__global__ __launch_bounds__(256) void k_aggv(const float* __restrict__ in,
    const int* __restrict__ rowptr, const int* __restrict__ esrc,
    float* __restrict__ out, int n) {
  int wid = ((blockIdx.x * 256) + threadIdx.x) >> 6;
  int lane = threadIdx.x & 63;
  if (wid >= n) return;
  int beg = rowptr[wid], end = rowptr[wid + 1];
  float s = 0.f;
  for (int e = beg + lane; e < end; e += 64) s += in[esrc[e]];
  for (int off = 32; off; off >>= 1) s += __shfl_down(s, off);
  if (lane == 0) out[wid] = s;
}

// ---------------- Gram on planar inputs: partial[z] = X^T Y over row chunk ----------------
// 128x128 tile, 256 thr, 8x8 acc with split fragments {t*4, 64+t*4}; LDS rows padded to 132.
__global__ __launch_bounds__(256) void k_gram(const float* __restrict__ Xm,
    const float* __restrict__ Ym, float* __restrict__ partial, int N) {
  __shared__ float Xs[16][132];
  __shared__ float Ys[16][132];
  int tid = threadIdx.x;
  int i0 = blockIdx.x * 128, j0 = blockIdx.y * 128;
  int z = blockIdx.z;
  int chunk = (N + GRAM_KS - 1) / GRAM_KS;
  int rb = z * chunk, re = min(N, rb + chunk);
  int lk = tid >> 4;          // 0..15 k-row
  int tj = tid & 15;
  int lc = tj * 8;            // col group for staging
  int ti = lk;                // row group for compute
  float acc[8][8] = {};
  for (int rr = rb; rr < re; rr += 16) {
    int r = rr + lk;
    float4 a0 = {0,0,0,0}, a1 = {0,0,0,0}, b0 = {0,0,0,0}, b1 = {0,0,0,0};
    if (r < re) {
      int Cx = i0 + lc, Cy = j0 + lc;
      const float* xp = Xm + ((size_t)(Cx >> 4) * N + r) * 16 + (Cx & 15);
      const float* yp = Ym + ((size_t)(Cy >> 4) * N + r) * 16 + (Cy & 15);
      a0 = *(const float4*)xp; a1 = *(const float4*)(xp + 4);
      b0 = *(const float4*)yp; b1 = *(const float4*)(yp + 4);
    }
    *(float4*)&Xs[lk][lc] = a0; *(float4*)&Xs[lk][lc + 4] = a1;
    *(float4*)&Ys[lk][lc] = b0; *(float4*)&Ys[lk][lc + 4] = b1;
    __syncthreads();
#pragma unroll
    for (int k = 0; k < 16; ++k) {
      float av[8], bv[8];
      *(float4*)&av[0] = *(const float4*)&Xs[k][ti * 4];
      *(float4*)&av[4] = *(const float4*)&Xs[k][64 + ti * 4];
      *(float4*)&bv[0] = *(const float4*)&Ys[k][tj * 4];
      *(float4*)&bv[4] = *(const float4*)&Ys[k][64 + tj * 4];
#pragma unroll
      for (int i = 0; i < 8; ++i)
#pragma unroll
        for (int j = 0; j < 8; ++j) acc[i][j] += av[i] * bv[j];
    }
    __syncthreads();
  }
  float* pout = partial + (size_t)z * 65536;
#pragma unroll
  for (int i = 0; i < 8; ++i) {
    int row = i0 + ((i < 4) ? (ti * 4 + i) : (64 + ti * 4 + i - 4));
#pragma unroll
    for (int j = 0; j < 8; j += 4) {
      int col = j0 + ((j < 4) ? (tj * 4 + j) : (64 + tj * 4 + j - 4));
      *(float4*)(pout + (size_t)row * 256 + col) = *(float4*)&acc[i][j];
    }
  }
}

__global__ void k_gram_reduce(const float* __restrict__ partial, float* __restrict__ C) {
  int idx = blockIdx.x * 256 + threadIdx.x;
  float s = 0.f;
  for (int z = 0; z < GRAM_KS; ++z) s += partial[(size_t)z * 65536 + idx];
  C[idx] = s;
}

// ---------------- weighted column sums (planar G) ----------------
__global__ __launch_bounds__(256) void k_matvec3(const float* __restrict__ G,
    const float* __restrict__ wA, const float* __restrict__ wB,
    float* outA, float* outB, float* outS, int n) {
  int f = threadIdx.x;
  size_t pbase = ((size_t)(f >> 4) * n) * 16 + (f & 15);
  float sA = 0.f, sB = 0.f, sS = 0.f;
  for (int r = blockIdx.x; r < n; r += gridDim.x) {
    float v = G[pbase + (size_t)r * 16];
    if (wA) sA += v * wA[r];
    if (wB) sB += v * wB[r];
    sS += v;
  }
  if (outA) atomicAdd(&outA[f], sA);
  if (outB) atomicAdd(&outB[f], sB);
  atomicAdd(&outS[f], sS);
}

// ---------------- 8 scalar reductions over d/e vectors ----------------
__global__ __launch_bounds__(256) void k_dots(const float* __restrict__ d1,
    const float* __restrict__ e1, const float* __restrict__ d2,
    const float* __restrict__ e2, float* scal, int n) {
  int i = blockIdx.x * 256 + threadIdx.x;
  float a = 0, b = 0, c = 0, d = 0;
  if (i < n) { a = d1[i]; b = e1[i]; c = d2[i]; d = e2[i]; }
  float v[8] = { b * d, b * c, b, a * d, a * c, a, d, c };
#pragma unroll
  for (int j = 0; j < 8; ++j) {
    float x = v[j];
    for (int off = 32; off; off >>= 1) x += __shfl_down(x, off);
    v[j] = x;
  }
  if ((threadIdx.x & 63) == 0)
#pragma unroll
    for (int j = 0; j < 8; ++j) atomicAdd(&scal[j], v[j]);
}

// ---------------- t_j = w_j^T C w_j ; mv_j = w_j . m_raw ----------------
__global__ __launch_bounds__(256) void k_quad(const float* __restrict__ C,
    const float* __restrict__ W1, const float* __restrict__ m_raw,
    float* __restrict__ t, float* __restrict__ mv) {
  __shared__ float w[256];
  __shared__ float r1[256], r2[256];
  int j = blockIdx.x, tid = threadIdx.x;
  w[tid] = W1[j * 256 + tid];
  __syncthreads();
  float v = 0.f;
  for (int k = 0; k < 256; ++k) v += w[k] * C[k * 256 + tid];
  r1[tid] = v * w[tid];
  r2[tid] = w[tid] * m_raw[tid];
  __syncthreads();
  for (int off = 128; off; off >>= 1) {
    if (tid < off) { r1[tid] += r1[tid + off]; r2[tid] += r2[tid + off]; }
    __syncthreads();
  }
  if (tid == 0) { t[j] = r1[0]; mv[j] = r2[0]; }
}

// ---------------- BN coefficients + x = W3 W2 c, y = W3 b2 ----------------
__global__ __launch_bounds__(256) void k_bncoef(const float* __restrict__ t,
    const float* __restrict__ mv, const float* __restrict__ b1,
    const float* __restrict__ gamma, const float* __restrict__ beta,
    const float* __restrict__ W2, const float* __restrict__ W3,
    const float* __restrict__ b2, float* Dv, float* xv, float* yv, int n) {
  __shared__ float c[256], u[256];
  int j = threadIdx.x;
  float invn = 1.f / (float)n;
  float mean = mv[j] * invn + b1[j];
  float E2 = t[j] * invn + 2.f * b1[j] * mv[j] * invn + b1[j] * b1[j];
  float var = E2 - mean * mean;
  float D = gamma[j] * rsqrtf(var + 1e-5f);
  Dv[j] = D;
  c[j] = D * (b1[j] - mean) + beta[j];
  __syncthreads();
  float uu = 0.f;
  for (int k = 0; k < 256; ++k) uu += W2[j * 256 + k] * c[k];
  u[j] = uu;
  __syncthreads();
  float xx = 0.f, yy = 0.f;
  for (int k = 0; k < 256; ++k) {
    xx += W3[j * 256 + k] * u[k];
    yy += W3[j * 256 + k] * b2[k];
  }
  xv[j] = xx;
  yv[j] = yy;
}

// ---------------- small 256x256 matmul ----------------
__global__ __launch_bounds__(256) void k_mm_small(float* __restrict__ Cm,
    const float* __restrict__ A, const float* __restrict__ B,
    const float* __restrict__ s, int transA, int transB, int accum) {
  __shared__ float a[256];
  int i = blockIdx.x, j = threadIdx.x;
  float av = transA ? A[j * 256 + i] : A[i * 256 + j];
  a[j] = s ? av * s[j] : av;
  __syncthreads();
  float acc = 0.f;
  if (transB) {
    for (int k = 0; k < 256; ++k) acc += a[k] * B[j * 256 + k];
  } else {
    for (int k = 0; k < 256; ++k) acc += a[k] * B[k * 256 + j];
  }
  if (accum) Cm[i * 256 + j] += acc;
  else Cm[i * 256 + j] = acc;
}

// ---------------- C (+)= u1 v1^T + u2 v2^T + u3 v3^T ----------------
__global__ void k_r1x3(float* __restrict__ C, const float* __restrict__ u1,
    const float* __restrict__ v1, const float* __restrict__ u2,
    const float* __restrict__ v2, const float* __restrict__ u3,
    const float* __restrict__ v3, int accum) {
  int i = blockIdx.x, j = threadIdx.x;
  float val = u1[i] * v1[j] + u2[i] * v2[j] + u3[i] * v3[j];
  if (accum) C[i * 256 + j] += val;
  else C[i * 256 + j] = val;
}

__global__ void k_mixvec(const float* __restrict__ scal, const float* __restrict__ x2,
    const float* __restrict__ yv, const float* __restrict__ b3,
    float* s1, float* s2, float* s3, float fN) {
  int j = threadIdx.x;
  s1[j] = scal[0] * x2[j] + scal[1] * yv[j] + scal[2] * b3[j];
  s2[j] = scal[3] * x2[j] + scal[4] * yv[j] + scal[5] * b3[j];
  s3[j] = scal[6] * x2[j] + scal[7] * yv[j] + fN * b3[j];
}

extern "C" void kernel_launch(void* const* d_in, const int* in_sizes, int n_in,
                              void* d_out, int out_size, void* d_ws, size_t ws_size,
                              hipStream_t stream) {
  const float* feature = (const float*)d_in[0];
  const int* src1 = (const int*)d_in[1];
  const int* dst1 = (const int*)d_in[2];
  const int* src2 = (const int*)d_in[3];
  const int* dst2 = (const int*)d_in[4];
  const float* W1 = (const float*)d_in[5];
  const float* b1 = (const float*)d_in[6];
  const float* W2 = (const float*)d_in[7];
  const float* b2 = (const float*)d_in[8];
  const float* W3 = (const float*)d_in[9];
  const float* b3 = (const float*)d_in[10];
  const float* gamma = (const float*)d_in[11];
  const float* beta = (const float*)d_in[12];
  const int N = in_sizes[0] / FDIM;
  const int E = in_sizes[1];
  float* out = (float*)d_out;

  // ---- workspace layout ----
  float* X = (float*)d_ws;
  size_t NF = (size_t)N * FDIM;
  float* Y = X + NF;
  float* G2A = Y + NF;
  int* rowptr = (int*)(G2A + NF);
  int* cursor = rowptr + (N + 1);
  int* esrc = cursor + N;
  float* vtmp = (float*)(esrc + E);
  float* d1 = vtmp + N; float* e1 = d1 + N; float* d2 = e1 + N; float* e2 = d2 + N;
  float* C = e2 + N;
  float* m_raw = C + 65536;
  float* tq = m_raw + 256; float* mv = tq + 256;
  float* Dv = mv + 256; float* x1 = Dv + 256; float* x2 = x1 + 256; float* yv = x2 + 256;
  float* Q = yv + 256; float* R1 = Q + 65536; float* R2 = R1 + 65536;
  float* Z = R2 + 65536; float* K1 = Z + 65536; float* Lm = K1 + 65536;
  float* p1 = Lm + 65536; float* p2 = p1 + 256; float* p3 = p2 + 256;
  float* q1 = p3 + 256; float* q2 = q1 + 256; float* q3 = q2 + 256;
  float* scal = q3 + 256;
  float* s1 = scal + 16; float* s2 = s1 + 256; float* s3 = s2 + 256;
  int* blksum = (int*)(s3 + 256);
  int* blkoff = blksum + 1024;
  float* FP = (float*)(blkoff + 1024);
  float* partial = X;   // GRAM_KS*65536 = 8.4M floats <= NF; X dead at gram time

  size_t need = (size_t)((char*)(FP + NF) - (char*)d_ws);
  int havePlanar = (ws_size >= need) ? 1 : 0;

  const int eb = (E + 255) / 256;
  const int nb = (N + 255) / 256;
  const int aggb = (N + 3) / 4;        // blocks of 4 nodes
  const int nblk = (N + 1023) / 1024;

  auto build = [&](const int* s_, const int* d_) {
    hipMemsetAsync(cursor, 0, (size_t)N * sizeof(int), stream);
    k_hist<<<eb, 256, 0, stream>>>(d_, cursor, E);
    k_blksum<<<nblk, 256, 0, stream>>>(cursor, blksum, N);
    k_blkscan<<<1, 64, 0, stream>>>(blksum, blkoff, nblk);
    k_scan_blk<<<nblk, 256, 0, stream>>>(cursor, blkoff, rowptr, cursor, N);
    k_scatter<<<eb, 256, 0, stream>>>(s_, d_, cursor, esrc, E);
  };
  auto agg = [&](const float* in, float* o, int rowmajor) {
    k_aggp<<<aggb * 8, 256, 0, stream>>>(in, rowptr, esrc, o, N, rowmajor);
  };
  auto gram = [&](const float* A_, const float* B_, float* Cout) {
    k_gram<<<dim3(2, 2, GRAM_KS), 256, 0, stream>>>(A_, B_, partial, N);
    k_gram_reduce<<<256, 256, 0, stream>>>(partial, Cout);
  };

  if (havePlanar) k_to_planar<<<(N + 3) / 4, 256, 0, stream>>>(feature, FP, N);

  auto do_branch = [&](const int* s_, const int* d_, float* G2dst,
                       float* dvec, float* evec, float* xvec, float* Rdst) {
    build(s_, d_);
    if (havePlanar) agg(FP, X, 0); else agg(feature, X, 1);
    agg(X, Y, 0);                               // Y = G0 (planar)
    gram(Y, Y, C);                              // C = G0^T G0
    hipMemsetAsync(m_raw, 0, 256 * sizeof(float), stream);
    k_matvec3<<<512, 256, 0, stream>>>(Y, nullptr, nullptr, nullptr, nullptr, m_raw, N);
    k_quad<<<256, 256, 0, stream>>>(C, W1, m_raw, tq, mv);
    k_bncoef<<<1, 256, 0, stream>>>(tq, mv, b1, gamma, beta, W2, W3, b2, Dv, xvec, yv, N);
    k_mm_small<<<256, 256, 0, stream>>>(Q, W1, W2, Dv, 1, 1, 0);
    k_mm_small<<<256, 256, 0, stream>>>(Rdst, Q, W3, nullptr, 0, 1, 0);
    k_deg<<<nb, 256, 0, stream>>>(rowptr, vtmp, N);
    k_aggv<<<aggb, 256, 0, stream>>>(vtmp, rowptr, esrc, dvec, N);   // d = A^2 1
    k_aggv<<<aggb, 256, 0, stream>>>(dvec, rowptr, esrc, vtmp, N);
    k_aggv<<<aggb, 256, 0, stream>>>(vtmp, rowptr, esrc, evec, N);   // e = A^4 1
    agg(Y, X, 0); agg(X, Y, 0);                 // Y = G1
    agg(Y, X, 0); agg(X, G2dst, 0);             // G2
  };

  do_branch(src1, dst1, G2A, d1, e1, x1, R1);
  do_branch(src2, dst2, Y, d2, e2, x2, R2);

  // ---- final assembly ----
  hipMemsetAsync(p1, 0, (6 * 256 + 16) * sizeof(float), stream);
  gram(G2A, Y, Z);                                                // Z = G2_1^T G2_2
  k_matvec3<<<512, 256, 0, stream>>>(G2A, e2, d2, p1, p2, p3, N);
  k_matvec3<<<512, 256, 0, stream>>>(Y, e1, d1, q1, q2, q3, N);
  k_dots<<<nb, 256, 0, stream>>>(d1, e1, d2, e2, scal, N);

  k_mm_small<<<256, 256, 0, stream>>>(K1, Z, R2, nullptr, 0, 0, 0);
  k_r1x3<<<256, 256, 0, stream>>>(K1, p1, x2, p2, yv, p3, b3, 1);
  k_r1x3<<<256, 256, 0, stream>>>(Lm, x1, q1, yv, q2, b3, q3, 0);
  k_mm_small<<<256, 256, 0, stream>>>(out, R1, K1, nullptr, 1, 0, 0);
  k_mm_small<<<256, 256, 0, stream>>>(out, Lm, R2, nullptr, 0, 0, 1);
  k_mixvec<<<1, 256, 0, stream>>>(scal, x2, yv, b3, s1, s2, s3, (float)N);
  k_r1x3<<<256, 256, 0, stream>>>(out, x1, s1, yv, s2, b3, s3, 1);
}